// Round 2
// baseline (18831.168 us; speedup 1.0000x reference)
//
#include <hip/hip_runtime.h>
#include <hip/hip_bf16.h>
#include <hip/hip_cooperative_groups.h>
#include <cstdio>

namespace cg = cooperative_groups;

#define NBATCH 64
#define TSTEPS 512
#define DDIM   1024
#define HDIM   1024
#define ACOLS  4096
#define NBLK   256
#define NTHR   256
#define HCB    4      // h-cols per block
#define KPX    1032   // padded LDS k-stride (elements): 2064B rows -> conflict-free-ish b128

typedef __attribute__((ext_vector_type(8))) short bf16x8;
typedef __attribute__((ext_vector_type(4))) float f32x4;

__device__ __forceinline__ unsigned short f2bf_bits(float f) {
  __hip_bfloat16 h = __float2bfloat16(f);
  return *(unsigned short*)&h;
}
__device__ __forceinline__ float bfbits2f(unsigned short u) {
  __hip_bfloat16 h = *(__hip_bfloat16*)&u;
  return __bfloat162float(h);
}

// Persistent cooperative LSTM. fp32 I/O.
// Block b owns h-cols [4b,4b+4) -> 16 a-cols (4 gates x 4), weights in LDS:
//   Wx as bf16 (x errors don't compound), Wh as hi+lo bf16 (h-feedback must be ~exact).
// Per step: x-half GEMM (no h dep) BEFORE grid.sync to absorb barrier slack, then
// h-half with 3-MFMA split (hihi + hilo + lohi), gates, fp32 out + hi/lo h planes.
__global__ __launch_bounds__(NTHR, 1)
void lstm_kernel(const float* __restrict__ xf,
                 const float* __restrict__ h0,
                 const float* __restrict__ Wx,
                 const float* __restrict__ Wh,
                 const float* __restrict__ bias,
                 float* __restrict__ out,
                 __hip_bfloat16* __restrict__ xh,   // ws: x as bf16 [64][512][1024]
                 __hip_bfloat16* __restrict__ hpl)  // ws: h planes [slot][hi|lo][64][1024]
{
  extern __shared__ char smem[];
  short* sWx  = (short*)smem;             // [16][KPX]
  short* sWhh = sWx  + 16 * KPX;          // [16][KPX]
  short* sWhl = sWhh + 16 * KPX;          // [16][KPX]
  float* accb = (float*)(sWhl + 16 * KPX);// [64][16]

  const int blk  = blockIdx.x;
  const int tid  = threadIdx.x;
  const int lane = tid & 63;
  const int wave = tid >> 6;
  cg::grid_group grid = cg::this_grid();
  const int gid = blk * NTHR + tid;

  // ---- prologue: x (fp32) -> bf16 plane, grid-strided ----
  {
    unsigned short* xhb = (unsigned short*)xh;
    const long NX = (long)NBATCH * TSTEPS * DDIM;
    for (long i = (long)gid * 4; i < NX; i += (long)NBLK * NTHR * 4) {
      const float4 v = *(const float4*)(xf + i);
      ushort4 pk;
      pk.x = f2bf_bits(v.x); pk.y = f2bf_bits(v.y);
      pk.z = f2bf_bits(v.z); pk.w = f2bf_bits(v.w);
      *(ushort4*)(xhb + i) = pk;
    }
  }
  // ---- prologue: h0 -> slot0 hi/lo planes ----
  for (int i = gid; i < NBATCH * HDIM; i += NBLK * NTHR) {
    const float v = h0[i];
    __hip_bfloat16 hb = __float2bfloat16(v);
    hpl[i] = hb;
    hpl[NBATCH * HDIM + i] = __float2bfloat16(v - __bfloat162float(hb));
  }
  // ---- prologue: W slabs -> LDS (fp32 reads, one-time) ----
  for (int it = tid; it < DDIM * 4; it += NTHR) {
    const int k = it >> 2;
    const int g = it & 3;
    const float4 wx = *(const float4*)(Wx + (size_t)k * ACOLS + g * HDIM + blk * HCB);
    const float4 wh = *(const float4*)(Wh + (size_t)k * ACOLS + g * HDIM + blk * HCB);
    const float* wxp = &wx.x;
    const float* whp = &wh.x;
    #pragma unroll
    for (int j = 0; j < 4; ++j) {
      const int c = g * 4 + j;
      sWx[c * KPX + k] = (short)f2bf_bits(wxp[j]);
      const unsigned short hb = f2bf_bits(whp[j]);
      sWhh[c * KPX + k] = (short)hb;
      sWhl[c * KPX + k] = (short)f2bf_bits(whp[j] - bfbits2f(hb));
    }
  }

  // ---- gate-thread constants: thread t -> (n = t>>2, j = t&3); global col = blk*4+j ----
  const int gn = tid >> 2;
  const int gj = tid & 3;
  float bb[4];
  #pragma unroll
  for (int g = 0; g < 4; ++g) bb[g] = bias[g * HDIM + blk * HCB + gj];
  float cst = 0.0f;

  // ---- MFMA lane geometry (wave w owns batch rows [16w,16w+16)) ----
  const int arow_n = wave * 16 + (lane & 15);
  const int kgrp   = (lane >> 4) * 8;
  const __hip_bfloat16* xrow_base = xh + (size_t)arow_n * (TSTEPS * DDIM) + kgrp;
  const short* bxp  = sWx  + (lane & 15) * KPX + kgrp;
  const short* bhhp = sWhh + (lane & 15) * KPX + kgrp;
  const short* bhlp = sWhl + (lane & 15) * KPX + kgrp;

  grid.sync();  // xh plane + h0 planes + LDS slabs ready

  for (int s = 0; s < TSTEPS; ++s) {
    f32x4 acc = {0.f, 0.f, 0.f, 0.f};

    // ---- x-half (k 0..1023), plain bf16, 1 MFMA/chunk; runs BEFORE the sync ----
    {
      const __hip_bfloat16* xr = xrow_base + (size_t)s * DDIM;
      bf16x8 A[4], B[4];
      #pragma unroll
      for (int p = 0; p < 4; ++p) {
        A[p] = *(const bf16x8*)(xr + p * 32);
        B[p] = *(const bf16x8*)(bxp + p * 32);
      }
      #pragma unroll
      for (int i = 0; i < 32; ++i) {
        const int sl = i & 3;
        acc = __builtin_amdgcn_mfma_f32_16x16x32_bf16(A[sl], B[sl], acc, 0, 0, 0);
        if (i < 28) {
          A[sl] = *(const bf16x8*)(xr + (i + 4) * 32);
          B[sl] = *(const bf16x8*)(bxp + (i + 4) * 32);
        }
      }
    }

    grid.sync();  // h_s (written by all blocks at end of step s-1) now visible

    // ---- h-half (k 0..1023), split hi/lo, 3 MFMAs/chunk, 8-deep prefetch ----
    {
      const __hip_bfloat16* hh = hpl + (size_t)(s & 1) * (2 * NBATCH * HDIM)
                                     + (size_t)arow_n * HDIM + kgrp;
      const __hip_bfloat16* hl = hh + NBATCH * HDIM;
      bf16x8 Ah[8], Al[8], Bh[8], Bl[8];
      #pragma unroll
      for (int p = 0; p < 8; ++p) {
        Ah[p] = *(const bf16x8*)(hh + p * 32);
        Al[p] = *(const bf16x8*)(hl + p * 32);
        Bh[p] = *(const bf16x8*)(bhhp + p * 32);
        Bl[p] = *(const bf16x8*)(bhlp + p * 32);
      }
      #pragma unroll
      for (int i = 0; i < 32; ++i) {
        const int sl = i & 7;
        acc = __builtin_amdgcn_mfma_f32_16x16x32_bf16(Ah[sl], Bh[sl], acc, 0, 0, 0);
        acc = __builtin_amdgcn_mfma_f32_16x16x32_bf16(Ah[sl], Bl[sl], acc, 0, 0, 0);
        acc = __builtin_amdgcn_mfma_f32_16x16x32_bf16(Al[sl], Bh[sl], acc, 0, 0, 0);
        if (i < 24) {
          Ah[sl] = *(const bf16x8*)(hh + (i + 8) * 32);
          Al[sl] = *(const bf16x8*)(hl + (i + 8) * 32);
          Bh[sl] = *(const bf16x8*)(bhhp + (i + 8) * 32);
          Bl[sl] = *(const bf16x8*)(bhlp + (i + 8) * 32);
        }
      }
    }

    // ---- partials to LDS: C/D layout col=lane&15, row=(lane>>4)*4+reg ----
    {
      const int q = lane >> 4;
      #pragma unroll
      for (int r = 0; r < 4; ++r)
        accb[(wave * 16 + q * 4 + r) * 16 + (lane & 15)] = acc[r];
    }
    __syncthreads();

    // ---- gates (local col c = g*4+j): i,f,o,g -> c,h; fp32 out + hi/lo h planes ----
    {
      float av[4];
      #pragma unroll
      for (int g = 0; g < 4; ++g) av[g] = accb[gn * 16 + g * 4 + gj] + bb[g];
      const float ig = 1.0f / (1.0f + __expf(-av[0]));
      const float fg = 1.0f / (1.0f + __expf(-av[1]));
      const float og = 1.0f / (1.0f + __expf(-av[2]));
      const float gg = tanhf(av[3]);
      cst = fg * cst + ig * gg;
      const float hv = og * tanhf(cst);
      out[(size_t)gn * (TSTEPS * HDIM) + (size_t)s * HDIM + blk * HCB + gj] = hv;
      __hip_bfloat16* nh = hpl + (size_t)((s + 1) & 1) * (2 * NBATCH * HDIM)
                               + gn * HDIM + blk * HCB + gj;
      const __hip_bfloat16 hb = __float2bfloat16(hv);
      nh[0] = hb;
      nh[NBATCH * HDIM] = __float2bfloat16(hv - __bfloat162float(hb));
    }
    // next iteration's grid.sync orders accb reuse and h-plane visibility
  }
}

extern "C" void kernel_launch(void* const* d_in, const int* in_sizes, int n_in,
                              void* d_out, int out_size, void* d_ws, size_t ws_size,
                              hipStream_t stream) {
  const float* x  = (const float*)d_in[0];
  const float* h0 = (const float*)d_in[1];
  const float* Wx = (const float*)d_in[2];
  const float* Wh = (const float*)d_in[3];
  const float* b  = (const float*)d_in[4];
  float* out = (float*)d_out;

  __hip_bfloat16* xh  = (__hip_bfloat16*)d_ws;                       // 64 MiB
  __hip_bfloat16* hpl = (__hip_bfloat16*)((char*)d_ws + (size_t)NBATCH*TSTEPS*DDIM*2); // 512 KiB

  const size_t smem = (size_t)(3 * 16 * KPX * 2) + (size_t)(64 * 16 * 4);  // 103168 B
  hipError_t e1 = hipFuncSetAttribute((const void*)lstm_kernel,
                                      hipFuncAttributeMaxDynamicSharedMemorySize, (int)smem);

  void* args[] = { (void*)&x, (void*)&h0, (void*)&Wx, (void*)&Wh, (void*)&b,
                   (void*)&out, (void*)&xh, (void*)&hpl };
  hipError_t e2 = hipLaunchCooperativeKernel((const void*)lstm_kernel, dim3(NBLK), dim3(NTHR),
                                             args, (unsigned)smem, stream);
  if (e1 != hipSuccess || e2 != hipSuccess)
    fprintf(stderr, "[lstm] setattr=%d launch=%d (%s)\n", (int)e1, (int)e2, hipGetErrorString(e2));
}

// Round 3
// 12366.521 us; speedup vs baseline: 1.5228x; 1.5228x over previous
//
#include <hip/hip_runtime.h>
#include <hip/hip_bf16.h>
#include <hip/hip_cooperative_groups.h>
#include <cstdio>

namespace cg = cooperative_groups;

#define NBATCH 64
#define TSTEPS 512
#define DDIM   1024
#define HDIM   1024
#define ACOLS  4096
#define NBLK   256
#define NTHR   256
#define HCB    4        // h-cols per block -> 16 a-cols
#define KPX    1032     // LDS k-stride: start-bank groups land 8 lanes / 4-bank group (balanced for b128)

typedef __attribute__((ext_vector_type(8))) short bf16x8;
typedef __attribute__((ext_vector_type(4))) float f32x4;
typedef unsigned int  u32;
typedef unsigned short u16;

__device__ __forceinline__ u16 bf_hi(float f) { __hip_bfloat16 h = __float2bfloat16(f); return *(u16*)&h; }
__device__ __forceinline__ float bf2f(u16 u)  { __hip_bfloat16 h = *(__hip_bfloat16*)&u; return __bfloat162float(h); }

union HU { u32 u[4]; bf16x8 v; };

// h fragment-plane indexing: element (row n, col k) ->
//   w=n>>4, r=n&15, c=k>>5, q=(k>>3)&3, j=k&7
//   bf16 idx = (w*32+c)*512 + 128*q + 8*r + j     (per-slot size 65536 bf16 = 32768 u32)
// Reader (wave w, chunk c, lane): contiguous 16B at u32 idx (w*32+c)*256 + 4*lane.

__global__ __launch_bounds__(NTHR, 1)
void lstm_kernel(const float* __restrict__ xf,
                 const float* __restrict__ h0,
                 const float* __restrict__ Wx,
                 const float* __restrict__ Wh,
                 const float* __restrict__ bias,
                 float* __restrict__ out,
                 u16* __restrict__ x_hi,   // ws: 64 MiB bf16 plane
                 u16* __restrict__ x_lo,   // ws: 64 MiB
                 u32* __restrict__ hslot,  // ws: 2 slots x 32768 u32 (fragment order, packed bf16 pairs)
                 u32* __restrict__ cnt)    // ws: 512 barrier counters
{
  extern __shared__ char smem[];
  short* sWxh = (short*)smem;               // [16][KPX]
  short* sWxl = sWxh + 16 * KPX;
  short* sWhh = sWxl + 16 * KPX;
  short* sWhl = sWhh + 16 * KPX;
  float* accb   = (float*)(sWhl + 16 * KPX); // [64][16]
  float* hstage = accb + 64 * 16;            // [64][4]

  const int blk  = blockIdx.x;
  const int tid  = threadIdx.x;
  const int lane = tid & 63;
  const int wave = tid >> 6;
  const int gid  = blk * NTHR + tid;
  cg::grid_group grid = cg::this_grid();

  // ================= phase 0: conversions + zero counters =================
  {
    const long NX = (long)NBATCH * TSTEPS * DDIM;
    for (long i = (long)gid * 4; i < NX; i += (long)NBLK * NTHR * 4) {
      const float4 v = *(const float4*)(xf + i);
      ushort4 hi, lo;
      hi.x = bf_hi(v.x); lo.x = bf_hi(v.x - bf2f(hi.x));
      hi.y = bf_hi(v.y); lo.y = bf_hi(v.y - bf2f(hi.y));
      hi.z = bf_hi(v.z); lo.z = bf_hi(v.z - bf2f(hi.z));
      hi.w = bf_hi(v.w); lo.w = bf_hi(v.w - bf2f(hi.w));
      *(ushort4*)(x_hi + i) = hi;
      *(ushort4*)(x_lo + i) = lo;
    }
    // h0 -> slot0 fragment plane (bf16 hi only)
    for (int i = gid; i < NBATCH * HDIM; i += NBLK * NTHR) {
      const int n = i >> 10, k = i & 1023;
      const int w = n >> 4, r = n & 15, c = k >> 5, q = (k >> 3) & 3, j = k & 7;
      ((u16*)hslot)[(w * 32 + c) * 512 + 128 * q + 8 * r + j] = bf_hi(h0[i]);
    }
    if (gid < TSTEPS) cnt[gid] = 0;
  }

  // ================= weight slabs -> LDS (hi/lo split) =================
  for (int it = tid; it < DDIM * 4; it += NTHR) {
    const int k = it & 1023, g = it >> 10;
    const float4 wx = *(const float4*)(Wx + (size_t)k * ACOLS + g * HDIM + blk * HCB);
    const float4 wh = *(const float4*)(Wh + (size_t)k * ACOLS + g * HDIM + blk * HCB);
    const float* wxp = &wx.x;
    const float* whp = &wh.x;
    #pragma unroll
    for (int j = 0; j < 4; ++j) {
      const int col = g * 4 + j;
      const u16 xh = bf_hi(wxp[j]);
      sWxh[col * KPX + k] = (short)xh;
      sWxl[col * KPX + k] = (short)bf_hi(wxp[j] - bf2f(xh));
      const u16 hh = bf_hi(whp[j]);
      sWhh[col * KPX + k] = (short)hh;
      sWhl[col * KPX + k] = (short)bf_hi(whp[j] - bf2f(hh));
    }
  }

  // gate-thread constants: thread t -> (n = t>>2, hc = t&3)
  const int gn = tid >> 2;
  const int ghc = tid & 3;
  float bb[4];
  #pragma unroll
  for (int g = 0; g < 4; ++g) bb[g] = bias[g * HDIM + blk * HCB + ghc];
  float cst = 0.0f;

  // h-writer constants: thread t<128 -> (nn = t>>1, p = t&1), k0 = blk*4+2p
  const int wn = tid >> 1;
  const int wp = tid & 1;
  int hw_idx = 0;
  {
    const int k0 = blk * HCB + 2 * wp;
    const int w2 = wn >> 4, r2 = wn & 15, c2 = k0 >> 5, q2 = (k0 >> 3) & 3, j0 = k0 & 7;
    hw_idx = (w2 * 32 + c2) * 256 + 64 * q2 + 4 * r2 + (j0 >> 1);
  }

  // MFMA lane geometry
  const int mrow = lane & 15;
  const int kq   = lane >> 4;
  const int n0   = wave * 16 + mrow;
  const u16* xh_row = x_hi + (size_t)n0 * (TSTEPS * DDIM) + 8 * kq;
  const u16* xl_row = x_lo + (size_t)n0 * (TSTEPS * DDIM) + 8 * kq;
  const short* bxh = sWxh + mrow * KPX + 8 * kq;
  const short* bxl = sWxl + mrow * KPX + 8 * kq;
  const short* bhh = sWhh + mrow * KPX + 8 * kq;
  const short* bhl = sWhl + mrow * KPX + 8 * kq;

  grid.sync();  // publishes x planes, h0 plane, zeroed counters (full fence once)

  for (int s = 0; s < TSTEPS; ++s) {
    f32x4 acc = {0.f, 0.f, 0.f, 0.f};

    // ---------- x-half: (xh+xl) @ (Wxh+Wxl), 3-term split; independent of h_s ----------
    {
      const u16* xh_p = xh_row + (size_t)s * DDIM;
      const u16* xl_p = xl_row + (size_t)s * DDIM;
      bf16x8 Ah[4], Al[4], Bh[4], Bl[4];
      #pragma unroll
      for (int p = 0; p < 4; ++p) {
        Ah[p] = *(const bf16x8*)(xh_p + p * 32);
        Al[p] = *(const bf16x8*)(xl_p + p * 32);
        Bh[p] = *(const bf16x8*)(bxh + p * 32);
        Bl[p] = *(const bf16x8*)(bxl + p * 32);
      }
      #pragma unroll
      for (int i = 0; i < 32; ++i) {
        const int sl = i & 3;
        acc = __builtin_amdgcn_mfma_f32_16x16x32_bf16(Ah[sl], Bh[sl], acc, 0, 0, 0);
        acc = __builtin_amdgcn_mfma_f32_16x16x32_bf16(Ah[sl], Bl[sl], acc, 0, 0, 0);
        acc = __builtin_amdgcn_mfma_f32_16x16x32_bf16(Al[sl], Bh[sl], acc, 0, 0, 0);
        if (i < 28) {
          Ah[sl] = *(const bf16x8*)(xh_p + (i + 4) * 32);
          Al[sl] = *(const bf16x8*)(xl_p + (i + 4) * 32);
          Bh[sl] = *(const bf16x8*)(bxh + (i + 4) * 32);
          Bl[sl] = *(const bf16x8*)(bxl + (i + 4) * 32);
        }
      }
    }

    // ---------- wait for h_s (all blocks' step s-1 writes) ----------
    if (s > 0) {
      if (tid == 0) {
        while (__hip_atomic_load(&cnt[s - 1], __ATOMIC_RELAXED, __HIP_MEMORY_SCOPE_AGENT) < NBLK)
          __builtin_amdgcn_s_sleep(1);
      }
      __syncthreads();
    }

    // ---------- h-half: h_hi @ (Whh+Whl), sc1 coalesced fragment loads ----------
    {
      const u32* hsrc = hslot + (size_t)(s & 1) * 32768;
      const u32* hbase = hsrc + 4 * lane;   // + (wave*32+c)*256
      HU A[8];
      bf16x8 Bh[8], Bl[8];
      #pragma unroll
      for (int p = 0; p < 8; ++p) {
        const u32* hp = hbase + (wave * 32 + p) * 256;
        #pragma unroll
        for (int m = 0; m < 4; ++m)
          A[p].u[m] = __hip_atomic_load((u32*)(hp + m), __ATOMIC_RELAXED, __HIP_MEMORY_SCOPE_AGENT);
        Bh[p] = *(const bf16x8*)(bhh + p * 32);
        Bl[p] = *(const bf16x8*)(bhl + p * 32);
      }
      #pragma unroll
      for (int i = 0; i < 32; ++i) {
        const int sl = i & 7;
        acc = __builtin_amdgcn_mfma_f32_16x16x32_bf16(A[sl].v, Bh[sl], acc, 0, 0, 0);
        acc = __builtin_amdgcn_mfma_f32_16x16x32_bf16(A[sl].v, Bl[sl], acc, 0, 0, 0);
        if (i < 24) {
          const u32* hp = hbase + (wave * 32 + i + 8) * 256;
          #pragma unroll
          for (int m = 0; m < 4; ++m)
            A[sl].u[m] = __hip_atomic_load((u32*)(hp + m), __ATOMIC_RELAXED, __HIP_MEMORY_SCOPE_AGENT);
          Bh[sl] = *(const bf16x8*)(bhh + (i + 8) * 32);
          Bl[sl] = *(const bf16x8*)(bhl + (i + 8) * 32);
        }
      }
    }

    // ---------- partials -> LDS (C/D: col=lane&15, row=(lane>>4)*4+reg) ----------
    #pragma unroll
    for (int r = 0; r < 4; ++r)
      accb[(wave * 16 + kq * 4 + r) * 16 + mrow] = acc[r];
    __syncthreads();

    // ---------- gates ----------
    {
      float av[4];
      #pragma unroll
      for (int g = 0; g < 4; ++g) av[g] = accb[gn * 16 + g * 4 + ghc] + bb[g];
      const float ig = 1.0f / (1.0f + __expf(-av[0]));
      const float fg = 1.0f / (1.0f + __expf(-av[1]));
      const float og = 1.0f / (1.0f + __expf(-av[2]));
      const float e2 = __expf(2.0f * av[3]);
      const float gg = (e2 - 1.0f) / (e2 + 1.0f);
      cst = fg * cst + ig * gg;
      const float e2c = __expf(2.0f * cst);
      const float hv = og * ((e2c - 1.0f) / (e2c + 1.0f));
      out[(size_t)gn * (TSTEPS * HDIM) + (size_t)s * HDIM + blk * HCB + ghc] = hv;
      hstage[gn * 4 + ghc] = hv;
    }
    __syncthreads();

    // ---------- publish h_{s+1}: packed bf16 pairs, sc1 stores ----------
    if (tid < 128) {
      const float v0 = hstage[wn * 4 + 2 * wp];
      const float v1 = hstage[wn * 4 + 2 * wp + 1];
      const u32 pk = (u32)bf_hi(v0) | ((u32)bf_hi(v1) << 16);
      u32* hdst = hslot + (size_t)((s + 1) & 1) * 32768;
      __hip_atomic_store(&hdst[hw_idx], pk, __ATOMIC_RELAXED, __HIP_MEMORY_SCOPE_AGENT);
    }
    asm volatile("s_waitcnt vmcnt(0)" ::: "memory");  // own h-stores (and out) at coherence point
    __syncthreads();
    if (tid == 0)
      __hip_atomic_fetch_add(&cnt[s], 1u, __ATOMIC_RELAXED, __HIP_MEMORY_SCOPE_AGENT);
  }
}

extern "C" void kernel_launch(void* const* d_in, const int* in_sizes, int n_in,
                              void* d_out, int out_size, void* d_ws, size_t ws_size,
                              hipStream_t stream) {
  const float* x  = (const float*)d_in[0];
  const float* h0 = (const float*)d_in[1];
  const float* Wx = (const float*)d_in[2];
  const float* Wh = (const float*)d_in[3];
  const float* b  = (const float*)d_in[4];
  float* out = (float*)d_out;

  const size_t XPL = (size_t)NBATCH * TSTEPS * DDIM * 2;  // 64 MiB per plane
  u16* x_hi  = (u16*)d_ws;
  u16* x_lo  = (u16*)((char*)d_ws + XPL);
  u32* hslot = (u32*)((char*)d_ws + 2 * XPL);             // 2 x 128 KiB
  u32* cnt   = (u32*)((char*)d_ws + 2 * XPL + 2 * 65536 * 2);

  const size_t smem = (size_t)(4 * 16 * KPX * 2) + (64 * 16 + 64 * 4) * sizeof(float); // 137216 B
  hipError_t e1 = hipFuncSetAttribute((const void*)lstm_kernel,
                                      hipFuncAttributeMaxDynamicSharedMemorySize, (int)smem);

  void* args[] = { (void*)&x, (void*)&h0, (void*)&Wx, (void*)&Wh, (void*)&b,
                   (void*)&out, (void*)&x_hi, (void*)&x_lo, (void*)&hslot, (void*)&cnt };
  hipError_t e2 = hipLaunchCooperativeKernel((const void*)lstm_kernel, dim3(NBLK), dim3(NTHR),
                                             args, (unsigned)smem, stream);
  if (e1 != hipSuccess || e2 != hipSuccess)
    fprintf(stderr, "[lstm] setattr=%d launch=%d (%s)\n", (int)e1, (int)e2, hipGetErrorString(e2));
}